// Round 12
// baseline (22.849 us; speedup 1.0000x reference)
//
#include <hip/hip_runtime.h>
#include <hip/hip_bf16.h>

#define L_ 30
#define NB 2
#define NN 64
#define NM 64
#define MCH 32

// ws float offsets
#define O_WAWQ 0        // 12x128
#define O_BQQ  1536     // 128
#define O_CK   1664     // 30x128
#define O_WEWK 5504     // 4x128
#define O_BOP  6016     // 128
#define O_SCT  6144     // ushort[128 c][168 k]  scal^T (masked-dense, bf16)
#define O_WOPT 16896    // ushort[128 e][128 c]  Wop^T (bf16)

typedef __attribute__((ext_vector_type(8))) short short8;
typedef __attribute__((ext_vector_type(4))) float f32x4;

__device__ __forceinline__ unsigned short f2b(float v) {
    union { float f; unsigned int u; } x; x.f = v;
    unsigned int u = x.u + 0x7FFFu + ((x.u >> 16) & 1u);
    return (unsigned short)(u >> 16);
}
__device__ __forceinline__ float dot4(float4 a, float4 b) {
    return a.x*b.x + a.y*b.y + a.z*b.z + a.w*b.w;
}

// kA: weight-only products, ONE row per block, 128-dot split 2x64 across
// thread halves, LDS combine. ROW MAP (Σ = 208 rows — R11 bug was 206):
//   [0,128)   WopT   d = b
//   [128,158) CV'    l = b-128   -> SCT D-rows
//   [158,162) WeWv   j = b-158   -> SCT P-rows   (4 rows! R11 had 2)
//   [162,192) Ck     l = b-162
//   [192,196) WeWk   j = b-192
//   [196,208) WaWq   f = b-196
// b==208: bqq(rr0)/bop(rr1) | b==209: SCT pad cols 136..167
__global__ __launch_bounds__(256)
void kA(const float* __restrict__ We,  const float* __restrict__ be,
        const float* __restrict__ Wa,  const float* __restrict__ ba,
        const float* __restrict__ pe,
        const float* __restrict__ Wq,  const float* __restrict__ bq,
        const float* __restrict__ Wk,  const float* __restrict__ bk,
        const float* __restrict__ Wv,  const float* __restrict__ bv,
        const float* __restrict__ Wo,  const float* __restrict__ bo,
        const float* __restrict__ Wp,  const float* __restrict__ bp,
        float* __restrict__ ws) {
    const int t = threadIdx.x;
    const int b = blockIdx.x;
    const int e = t & 127;
    const int rr = t >> 7;
    unsigned short* SCT  = (unsigned short*)(ws + O_SCT);
    unsigned short* WOPT = (unsigned short*)(ws + O_WOPT);
    __shared__ float part[128];

    if (b < 208) {
        const float* xrow;          // row operand (broadcast across e)
        const float* Bmat;          // B[d*128+e]
        int kind, idx;
        if (b < 128)      { kind = 0; idx = b;      xrow = Wo + idx*128; Bmat = Wp; }
        else if (b < 158) { kind = 1; idx = b-128;  xrow = pe + idx*128; Bmat = Wv; }
        else if (b < 162) { kind = 2; idx = b-158;  xrow = We + idx*128; Bmat = Wv; }
        else if (b < 192) { kind = 3; idx = b-162;  xrow = pe + idx*128; Bmat = Wk; }
        else if (b < 196) { kind = 4; idx = b-192;  xrow = We + idx*128; Bmat = Wk; }
        else              { kind = 5; idx = b-196;  xrow = Wa + idx*128; Bmat = Wq; }
        const bool addbe = (kind == 1 || kind == 3);   // (be + pe_l)
        float acc = 0.f;
        const int d0 = rr * 64;
        #pragma unroll 32
        for (int d = 0; d < 64; ++d) {
            float xv = xrow[d0 + d];
            if (addbe) xv += be[d0 + d];
            acc += xv * Bmat[(d0 + d)*128 + e];
        }
        if (rr == 1) part[e] = acc;
        __syncthreads();
        if (rr == 0) {
            float total = acc + part[e];
            if (kind == 0) {
                WOPT[e*128 + idx] = f2b(total);
            } else if (kind == 1) {
                total += bv[e];
                const int h = e >> 5;
                unsigned short v = f2b(total);
                #pragma unroll
                for (int hh = 0; hh < 4; ++hh)
                    SCT[e*168 + 16 + hh*30 + idx] = (hh == h) ? v : (unsigned short)0;
            } else if (kind == 2) {
                const int h = e >> 5;
                unsigned short v = f2b(total);
                #pragma unroll
                for (int hh = 0; hh < 4; ++hh)
                    SCT[e*168 + hh*4 + idx] = (hh == h) ? v : (unsigned short)0;
            } else if (kind == 3) {
                ws[O_CK + idx*128 + e] = total + bk[e];
            } else if (kind == 4) {
                ws[O_WEWK + idx*128 + e] = total;
            } else {
                ws[O_WAWQ + idx*128 + e] = total;
            }
        }
    } else if (b == 208) {
        if (rr == 0) {                  // bqq[e] = ba@Wq[:,e] + bq[e]
            float acc = bq[e];
            #pragma unroll 32
            for (int d = 0; d < 128; ++d) acc += ba[d] * Wq[d*128 + e];
            ws[O_BQQ + e] = acc;
        } else {                        // bop[e] = bo@Wp[:,e] + bp[e]
            float acc = bp[e];
            #pragma unroll 32
            for (int d = 0; d < 128; ++d) acc += bo[d] * Wp[d*128 + e];
            ws[O_BOP + e] = acc;
        }
    } else {                            // pad SCT cols 136..167
        for (int i = t; i < 128*32; i += 256) {
            int c = i >> 5, k = 136 + (i & 31);
            SCT[c*168 + k] = 0;
        }
    }
}

// 256 blocks, 32 m's each (bn = bid>>1, m0 = (bid&1)*32).
// P0 {frag prefetch, qs, edges} / P1 {u,c} / P2 {scores+softmax+we4}
// / P3 {T = Wc@scalT, 20 MFMA} / P4 {out = T@Wop + bop, 16 MFMA}
__global__ __launch_bounds__(256)
void k_main(const float* __restrict__ agent, const float* __restrict__ lane,
            const float* __restrict__ ws, float* __restrict__ out) {

    __shared__ __align__(16) float ScE[MCH][124];             // edges f32 [m][l*4+j]
    __shared__ __align__(16) unsigned short WcB[MCH][168];    // bf16: we4 | w | pad
    __shared__ __align__(16) unsigned short T_s[MCH][136];    // bf16 T
    __shared__ __align__(16) float uc_s[136];                 // u(16) | c(120)
    __shared__ __align__(16) float qs_s[128];

    const int t = threadIdx.x;
    const int bid = blockIdx.x;
    const int bn = bid >> 1;
    const int m0 = (bid & 1) * MCH;
    const int b = bn >> 6;

    // ---- P0 ----
    const unsigned short* SCT  = (const unsigned short*)(ws + O_SCT);
    const unsigned short* WOPT = (const unsigned short*)(ws + O_WOPT);
    const int lane_id = t & 63;
    const int wv = t >> 6;
    const int frm = lane_id & 15;
    const int kg  = lane_id >> 4;
    const int e0 = wv*32 + frm;
    short8 s0[5], s1[5];
    #pragma unroll
    for (int i = 0; i < 5; ++i) {
        s0[i] = *(const short8*)&SCT[e0*168 + i*32 + kg*8];
        s1[i] = *(const short8*)&SCT[(e0+16)*168 + i*32 + kg*8];
    }
    short8 w0[4], w1[4];
    #pragma unroll
    for (int i = 0; i < 4; ++i) {
        w0[i] = *(const short8*)&WOPT[e0*128 + i*32 + kg*8];
        w1[i] = *(const short8*)&WOPT[(e0+16)*128 + i*32 + kg*8];
    }
    const float bb0 = ws[O_BOP + e0];
    const float bb1 = ws[O_BOP + e0 + 16];

    if (t < 128) {                       // qs
        const float* ag = agent + bn*16;
        float acc = ws[O_BQQ + t];
        acc += ag[2] * ws[O_WAWQ + t];
        #pragma unroll
        for (int f = 1; f < 12; ++f) acc += ag[4+f] * ws[O_WAWQ + f*128 + t];
        qs_s[t] = acc * 0.17677669529663687f;
    }
    for (int i = t; i < MCH*32; i += 256) {      // WcB pad cols 136..167
        int m = i >> 5;
        WcB[m][136 + (i & 31)] = 0;
    }
    const float ax  = agent[bn*16+0], ay = agent[bn*16+1];
    const float as_ = agent[bn*16+3], ac = agent[bn*16+4];
    const float f1 = (ax==0.f && ay==0.f && as_==0.f && ac==0.f) ? 0.f : 1.f;
    for (int job = t; job < MCH*30; job += 256) {
        int m = job / 30, l = job - m*30;
        const float* lp = lane + (size_t)((b*NM + m0 + m)*L_ + l)*4;
        float4 lv = *(const float4*)lp;
        float f2 = (lv.x==0.f && lv.y==0.f && lv.z==0.f && lv.w==0.f) ? 0.f : 1.f;
        float f = f1 * f2;
        float dx = lv.x - ax, dy = lv.y - ay;
        float4 ev;
        ev.x = (ac*dx + as_*dy) * 0.1f * f;
        ev.y = (ac*dy - as_*dx) * 0.1f * f;
        ev.z = (lv.z*ac - lv.w*as_) * f;
        ev.w = (lv.w*ac + lv.z*as_) * f;
        *(float4*)&ScE[m][l*4] = ev;
    }
    __syncthreads();

    // ---- P1: u (4x4), c (4x30) from qs_s ----
    if (t < 136) {
        float a = 0.f;
        if (t < 16) {
            int h = t >> 2, j = t & 3;
            const float4* x = (const float4*)(ws + O_WEWK + j*128 + h*32);
            const float4* y = (const float4*)&qs_s[h*32];
            #pragma unroll
            for (int i = 0; i < 8; ++i) a += dot4(x[i], y[i]);
        } else {
            int r = t - 16; int h = r/30, l = r - h*30;
            const float4* x = (const float4*)(ws + O_CK + l*128 + h*32);
            const float4* y = (const float4*)&qs_s[h*32];
            #pragma unroll
            for (int i = 0; i < 8; ++i) a += dot4(x[i], y[i]);
        }
        uc_s[t] = a;
    }
    __syncthreads();

    // ---- P2: scores + pair softmax + fused we4 (32m x 4h x 2s, 15 l each) ----
    {
        const int m = t >> 3, hh = (t >> 1) & 3, s = t & 1;
        float4 u4 = *(const float4*)&uc_s[hh*4];
        float sc[15];
        float mx = -1e30f;
        #pragma unroll
        for (int k = 0; k < 15; ++k) {
            int l = s + 2*k;
            float4 e4 = *(const float4*)&ScE[m][l*4];
            sc[k] = e4.x*u4.x + e4.y*u4.y + e4.z*u4.z + e4.w*u4.w
                  + uc_s[16 + hh*30 + l];
            mx = fmaxf(mx, sc[k]);
        }
        mx = fmaxf(mx, __shfl_xor(mx, 1, 64));
        float sum = 0.f;
        #pragma unroll
        for (int k = 0; k < 15; ++k) {
            float evv = __expf(sc[k] - mx);
            sc[k] = evv; sum += evv;
        }
        sum += __shfl_xor(sum, 1, 64);
        const float inv = 1.f / sum;
        float4 p = make_float4(0.f,0.f,0.f,0.f);
        #pragma unroll
        for (int k = 0; k < 15; ++k) {
            int l = s + 2*k;
            float w = sc[k] * inv;
            WcB[m][16 + hh*30 + l] = f2b(w);
            float4 e4 = *(const float4*)&ScE[m][l*4];
            p.x += w * e4.x; p.y += w * e4.y;
            p.z += w * e4.z; p.w += w * e4.w;
        }
        p.x += __shfl_xor(p.x, 1, 64); p.y += __shfl_xor(p.y, 1, 64);
        p.z += __shfl_xor(p.z, 1, 64); p.w += __shfl_xor(p.w, 1, 64);
        if (s == 0) {
            WcB[m][hh*4 + 0] = f2b(p.x);
            WcB[m][hh*4 + 1] = f2b(p.y);
        } else {
            WcB[m][hh*4 + 2] = f2b(p.z);
            WcB[m][hh*4 + 3] = f2b(p.w);
        }
    }
    __syncthreads();

    // ---- P3: T[32m x 128c] = WcB[32x160] @ scalT (20 MFMA) -> T_s bf16 ----
    {
        f32x4 a00 = {0.f,0.f,0.f,0.f}, a01 = {0.f,0.f,0.f,0.f};
        f32x4 a10 = {0.f,0.f,0.f,0.f}, a11 = {0.f,0.f,0.f,0.f};
        #pragma unroll
        for (int i = 0; i < 5; ++i) {
            short8 aL = *(const short8*)&WcB[frm][i*32 + kg*8];
            short8 aH = *(const short8*)&WcB[frm+16][i*32 + kg*8];
            a00 = __builtin_amdgcn_mfma_f32_16x16x32_bf16(aL, s0[i], a00, 0, 0, 0);
            a01 = __builtin_amdgcn_mfma_f32_16x16x32_bf16(aL, s1[i], a01, 0, 0, 0);
            a10 = __builtin_amdgcn_mfma_f32_16x16x32_bf16(aH, s0[i], a10, 0, 0, 0);
            a11 = __builtin_amdgcn_mfma_f32_16x16x32_bf16(aH, s1[i], a11, 0, 0, 0);
        }
        #pragma unroll
        for (int r = 0; r < 4; ++r) {
            T_s[kg*4 + r][e0]           = f2b(a00[r]);
            T_s[kg*4 + r][e0 + 16]      = f2b(a01[r]);
            T_s[16 + kg*4 + r][e0]      = f2b(a10[r]);
            T_s[16 + kg*4 + r][e0 + 16] = f2b(a11[r]);
        }
    }
    __syncthreads();

    // ---- P4: OUT[32m x 128e] = T @ Wop (16 MFMA), acc init = bop ----
    {
        f32x4 a00 = {bb0, bb0, bb0, bb0}, a01 = {bb1, bb1, bb1, bb1};
        f32x4 a10 = {bb0, bb0, bb0, bb0}, a11 = {bb1, bb1, bb1, bb1};
        #pragma unroll
        for (int i = 0; i < 4; ++i) {
            short8 aL = *(const short8*)&T_s[frm][i*32 + kg*8];
            short8 aH = *(const short8*)&T_s[frm+16][i*32 + kg*8];
            a00 = __builtin_amdgcn_mfma_f32_16x16x32_bf16(aL, w0[i], a00, 0, 0, 0);
            a01 = __builtin_amdgcn_mfma_f32_16x16x32_bf16(aL, w1[i], a01, 0, 0, 0);
            a10 = __builtin_amdgcn_mfma_f32_16x16x32_bf16(aH, w0[i], a10, 0, 0, 0);
            a11 = __builtin_amdgcn_mfma_f32_16x16x32_bf16(aH, w1[i], a11, 0, 0, 0);
        }
        float* ob = out + ((size_t)(bn*NM + m0))*128;
        #pragma unroll
        for (int r = 0; r < 4; ++r) {
            int mL = kg*4 + r, mH = 16 + kg*4 + r;
            ob[mL*128 + e0]      = a00[r];
            ob[mL*128 + e0 + 16] = a01[r];
            ob[mH*128 + e0]      = a10[r];
            ob[mH*128 + e0 + 16] = a11[r];
        }
    }
}

extern "C" void kernel_launch(void* const* d_in, const int* in_sizes, int n_in,
                              void* d_out, int out_size, void* d_ws, size_t ws_size,
                              hipStream_t stream) {
    const float* agent = (const float*)d_in[0];
    const float* lane  = (const float*)d_in[1];
    const float* We = (const float*)d_in[2];
    const float* be = (const float*)d_in[3];
    const float* Wa = (const float*)d_in[4];
    const float* ba = (const float*)d_in[5];
    const float* pe = (const float*)d_in[6];
    const float* Wq = (const float*)d_in[7];
    const float* bq = (const float*)d_in[8];
    const float* Wk = (const float*)d_in[9];
    const float* bk = (const float*)d_in[10];
    const float* Wv = (const float*)d_in[11];
    const float* bv = (const float*)d_in[12];
    const float* Wo = (const float*)d_in[13];
    const float* bo = (const float*)d_in[14];
    const float* Wp = (const float*)d_in[15];
    const float* bp = (const float*)d_in[16];
    float* ws  = (float*)d_ws;
    float* out = (float*)d_out;

    hipLaunchKernelGGL(kA, dim3(210), dim3(256), 0, stream,
                       We, be, Wa, ba, pe, Wq, bq, Wk, bk, Wv, bv, Wo, bo, Wp, bp, ws);
    hipLaunchKernelGGL(k_main, dim3(NB*NN*2), dim3(256), 0, stream,
                       agent, lane, ws, out);
}

// Round 13
// 21.333 us; speedup vs baseline: 1.0711x; 1.0711x over previous
//
#include <hip/hip_runtime.h>
#include <hip/hip_bf16.h>

#define L_ 30
#define NB 2
#define NN 64
#define NM 64
#define MCH 8

// ws float offsets
#define O_WAWQ 0        // 12x128
#define O_BQQ  1536     // 128
#define O_CK   1664     // 30x128
#define O_WEWK 5504     // 4x128
#define O_BOP  6016     // 128
#define O_SCT  6144     // ushort[128 c][168 k]  scal^T (masked-dense, bf16)
#define O_WOPT 16896    // ushort[128 e][128 c]  Wop^T (bf16)

typedef __attribute__((ext_vector_type(8))) short short8;
typedef __attribute__((ext_vector_type(4))) float f32x4;

__device__ __forceinline__ unsigned short f2b(float v) {
    union { float f; unsigned int u; } x; x.f = v;
    unsigned int u = x.u + 0x7FFFu + ((x.u >> 16) & 1u);
    return (unsigned short)(u >> 16);
}
__device__ __forceinline__ float dot4(float4 a, float4 b) {
    return a.x*b.x + a.y*b.y + a.z*b.z + a.w*b.w;
}

// kA (PROVEN R10 version): weight-only products, depth-1, thread-per-output,
// e=lane coalesced, unroll 32. Row check: 128+30+4+30+4+12 = 208 rows over
// 105 pair-blocks + bqq/bop + pad = 106 blocks.
__global__ __launch_bounds__(256)
void kA(const float* __restrict__ We,  const float* __restrict__ be,
        const float* __restrict__ Wa,  const float* __restrict__ ba,
        const float* __restrict__ pe,
        const float* __restrict__ Wq,  const float* __restrict__ bq,
        const float* __restrict__ Wk,  const float* __restrict__ bk,
        const float* __restrict__ Wv,  const float* __restrict__ bv,
        const float* __restrict__ Wo,  const float* __restrict__ bo,
        const float* __restrict__ Wp,  const float* __restrict__ bp,
        float* __restrict__ ws) {
    const int t = threadIdx.x;
    const int b = blockIdx.x;
    const int e = t & 127;
    const int rr = t >> 7;
    unsigned short* SCT  = (unsigned short*)(ws + O_SCT);
    unsigned short* WOPT = (unsigned short*)(ws + O_WOPT);

    if (b < 64) {                       // WopT[e][d] = Wo[d] @ Wp[:,e]
        const int d = 2*b + rr;
        const float* wo = Wo + d*128;
        float acc = 0.f;
        #pragma unroll 32
        for (int x = 0; x < 128; ++x) acc += wo[x] * Wp[x*128 + e];
        WOPT[e*128 + d] = f2b(acc);
    } else if (b < 79) {                // CV'[l][c]=(be+pe_l)@Wv[:,c]+bv -> SCT D-rows
        const int l = 2*(b-64) + rr;
        const int h = e >> 5;
        const float* pl = pe + l*128;
        float acc = bv[e];
        #pragma unroll 32
        for (int d = 0; d < 128; ++d) acc += (be[d] + pl[d]) * Wv[d*128 + e];
        unsigned short v = f2b(acc);
        #pragma unroll
        for (int hh = 0; hh < 4; ++hh)
            SCT[e*168 + 16 + hh*30 + l] = (hh == h) ? v : (unsigned short)0;
    } else if (b < 81) {                // WeWv[j][c] -> SCT P-rows
        const int j = 2*(b-79) + rr;
        const int h = e >> 5;
        const float* wj = We + j*128;
        float acc = 0.f;
        #pragma unroll 32
        for (int d = 0; d < 128; ++d) acc += wj[d] * Wv[d*128 + e];
        unsigned short v = f2b(acc);
        #pragma unroll
        for (int hh = 0; hh < 4; ++hh)
            SCT[e*168 + hh*4 + j] = (hh == h) ? v : (unsigned short)0;
    } else if (b < 96) {                // Ck[l][e] = (be+pe_l)@Wk[:,e]+bk
        const int l = 2*(b-81) + rr;
        const float* pl = pe + l*128;
        float acc = bk[e];
        #pragma unroll 32
        for (int d = 0; d < 128; ++d) acc += (be[d] + pl[d]) * Wk[d*128 + e];
        ws[O_CK + l*128 + e] = acc;
    } else if (b < 98) {                // WeWk[j][e]
        const int j = 2*(b-96) + rr;
        const float* wj = We + j*128;
        float acc = 0.f;
        #pragma unroll 32
        for (int d = 0; d < 128; ++d) acc += wj[d] * Wk[d*128 + e];
        ws[O_WEWK + j*128 + e] = acc;
    } else if (b < 104) {               // WaWq[f][e]
        const int f = 2*(b-98) + rr;
        const float* wf = Wa + f*128;
        float acc = 0.f;
        #pragma unroll 32
        for (int d = 0; d < 128; ++d) acc += wf[d] * Wq[d*128 + e];
        ws[O_WAWQ + f*128 + e] = acc;
    } else if (b == 104) {
        if (rr == 0) {                  // bqq[e] = ba@Wq[:,e] + bq[e]
            float acc = bq[e];
            #pragma unroll 32
            for (int d = 0; d < 128; ++d) acc += ba[d] * Wq[d*128 + e];
            ws[O_BQQ + e] = acc;
        } else {                        // bop[e] = bo@Wp[:,e] + bp[e]
            float acc = bp[e];
            #pragma unroll 32
            for (int d = 0; d < 128; ++d) acc += bo[d] * Wp[d*128 + e];
            ws[O_BOP + e] = acc;
        }
    } else {                            // pad SCT cols 136..167
        for (int i = t; i < 128*32; i += 256) {
            int c = i >> 5, k = 136 + (i & 31);
            SCT[c*168 + k] = 0;
        }
    }
}

// 1024 blocks, 8 m's each (bn = bid>>3, m0 = (bid&7)*8) -> ~4 blocks/CU.
// WcB has 16 rows: rows 8..15 stay zero (MFMA pad). P4 stores only m<8.
__global__ __launch_bounds__(256)
void k_main(const float* __restrict__ agent, const float* __restrict__ lane,
            const float* __restrict__ ws, float* __restrict__ out) {

    __shared__ __align__(16) float ScE[MCH][124];             // edges f32 [m][l*4+j]
    __shared__ __align__(16) unsigned short WcB[16][168];     // bf16: we4 | w | pad
    __shared__ __align__(16) unsigned short T_s[16][136];     // bf16 T
    __shared__ __align__(16) float uc_s[136];                 // u(16) | c(120)
    __shared__ __align__(16) float qs_s[128];

    const int t = threadIdx.x;
    const int bid = blockIdx.x;
    const int bn = bid >> 3;
    const int m0 = (bid & 7) * MCH;
    const int b = bn >> 6;

    // ---- P0: frag prefetch + qs + WcB zero + edges ----
    const unsigned short* SCT  = (const unsigned short*)(ws + O_SCT);
    const unsigned short* WOPT = (const unsigned short*)(ws + O_WOPT);
    const int lane_id = t & 63;
    const int wv = t >> 6;
    const int frm = lane_id & 15;
    const int kg  = lane_id >> 4;
    const int e0 = wv*32 + frm;
    short8 s0[5], s1[5];
    #pragma unroll
    for (int i = 0; i < 5; ++i) {
        s0[i] = *(const short8*)&SCT[e0*168 + i*32 + kg*8];
        s1[i] = *(const short8*)&SCT[(e0+16)*168 + i*32 + kg*8];
    }
    short8 w0[4], w1[4];
    #pragma unroll
    for (int i = 0; i < 4; ++i) {
        w0[i] = *(const short8*)&WOPT[e0*128 + i*32 + kg*8];
        w1[i] = *(const short8*)&WOPT[(e0+16)*128 + i*32 + kg*8];
    }
    const float bb0 = ws[O_BOP + e0];
    const float bb1 = ws[O_BOP + e0 + 16];

    if (t < 128) {                       // qs
        const float* ag = agent + bn*16;
        float acc = ws[O_BQQ + t];
        acc += ag[2] * ws[O_WAWQ + t];
        #pragma unroll
        for (int f = 1; f < 12; ++f) acc += ag[4+f] * ws[O_WAWQ + f*128 + t];
        qs_s[t] = acc * 0.17677669529663687f;
    }
    {   // zero ALL of WcB (16*168 ushorts = 336 uint4)
        uint4* dst = (uint4*)&WcB[0][0];
        for (int i = t; i < 336; i += 256) dst[i] = make_uint4(0,0,0,0);
    }
    const float ax  = agent[bn*16+0], ay = agent[bn*16+1];
    const float as_ = agent[bn*16+3], ac = agent[bn*16+4];
    const float f1 = (ax==0.f && ay==0.f && as_==0.f && ac==0.f) ? 0.f : 1.f;
    for (int job = t; job < MCH*30; job += 256) {
        int m = job / 30, l = job - m*30;
        const float* lp = lane + (size_t)((b*NM + m0 + m)*L_ + l)*4;
        float4 lv = *(const float4*)lp;
        float f2 = (lv.x==0.f && lv.y==0.f && lv.z==0.f && lv.w==0.f) ? 0.f : 1.f;
        float f = f1 * f2;
        float dx = lv.x - ax, dy = lv.y - ay;
        float4 ev;
        ev.x = (ac*dx + as_*dy) * 0.1f * f;
        ev.y = (ac*dy - as_*dx) * 0.1f * f;
        ev.z = (lv.z*ac - lv.w*as_) * f;
        ev.w = (lv.w*ac + lv.z*as_) * f;
        *(float4*)&ScE[m][l*4] = ev;
    }
    __syncthreads();

    // ---- P1: u (4x4), c (4x30) from qs_s ----
    if (t < 136) {
        float a = 0.f;
        if (t < 16) {
            int h = t >> 2, j = t & 3;
            const float4* x = (const float4*)(ws + O_WEWK + j*128 + h*32);
            const float4* y = (const float4*)&qs_s[h*32];
            #pragma unroll
            for (int i = 0; i < 8; ++i) a += dot4(x[i], y[i]);
        } else {
            int r = t - 16; int h = r/30, l = r - h*30;
            const float4* x = (const float4*)(ws + O_CK + l*128 + h*32);
            const float4* y = (const float4*)&qs_s[h*32];
            #pragma unroll
            for (int i = 0; i < 8; ++i) a += dot4(x[i], y[i]);
        }
        uc_s[t] = a;
    }
    __syncthreads();

    // ---- P2: scores + 8-lane softmax + fused we4 (8m x 4h x 8s, 4 slots) ----
    {
        const int m = t >> 5, hh = (t >> 3) & 3, s = t & 7;
        float4 u4 = *(const float4*)&uc_s[hh*4];
        float4 e4[4];
        float sc[4];
        float mx = -1e30f;
        #pragma unroll
        for (int k = 0; k < 4; ++k) {
            int l = s + 8*k;
            if (l < 30) {
                e4[k] = *(const float4*)&ScE[m][l*4];
                sc[k] = e4[k].x*u4.x + e4[k].y*u4.y + e4[k].z*u4.z + e4[k].w*u4.w
                      + uc_s[16 + hh*30 + l];
            } else {
                e4[k] = make_float4(0.f,0.f,0.f,0.f);
                sc[k] = -1e30f;
            }
            mx = fmaxf(mx, sc[k]);
        }
        mx = fmaxf(mx, __shfl_xor(mx, 1, 64));
        mx = fmaxf(mx, __shfl_xor(mx, 2, 64));
        mx = fmaxf(mx, __shfl_xor(mx, 4, 64));
        float sum = 0.f;
        float wvv[4];
        #pragma unroll
        for (int k = 0; k < 4; ++k) {
            float evv = __expf(sc[k] - mx);
            evv = (s + 8*k < 30) ? evv : 0.f;
            wvv[k] = evv; sum += evv;
        }
        sum += __shfl_xor(sum, 1, 64);
        sum += __shfl_xor(sum, 2, 64);
        sum += __shfl_xor(sum, 4, 64);
        const float inv = 1.f / sum;
        float4 p = make_float4(0.f,0.f,0.f,0.f);
        #pragma unroll
        for (int k = 0; k < 4; ++k) {
            int l = s + 8*k;
            if (l < 30) {
                float w = wvv[k] * inv;
                WcB[m][16 + hh*30 + l] = f2b(w);
                p.x += w * e4[k].x; p.y += w * e4[k].y;
                p.z += w * e4[k].z; p.w += w * e4[k].w;
            }
        }
        p.x += __shfl_xor(p.x, 1, 64); p.y += __shfl_xor(p.y, 1, 64);
        p.z += __shfl_xor(p.z, 1, 64); p.w += __shfl_xor(p.w, 1, 64);
        p.x += __shfl_xor(p.x, 2, 64); p.y += __shfl_xor(p.y, 2, 64);
        p.z += __shfl_xor(p.z, 2, 64); p.w += __shfl_xor(p.w, 2, 64);
        p.x += __shfl_xor(p.x, 4, 64); p.y += __shfl_xor(p.y, 4, 64);
        p.z += __shfl_xor(p.z, 4, 64); p.w += __shfl_xor(p.w, 4, 64);
        if (s < 4) {
            float mine = (s == 0) ? p.x : (s == 1) ? p.y : (s == 2) ? p.z : p.w;
            WcB[m][hh*4 + s] = f2b(mine);
        }
    }
    __syncthreads();

    // ---- P3: T[16 x 128c] = WcB[16x160] @ scalT (10 MFMA; rows 8..15 zero) ----
    {
        f32x4 a0 = {0.f,0.f,0.f,0.f};
        f32x4 a1 = {0.f,0.f,0.f,0.f};
        #pragma unroll
        for (int i = 0; i < 5; ++i) {
            short8 a = *(const short8*)&WcB[frm][i*32 + kg*8];
            a0 = __builtin_amdgcn_mfma_f32_16x16x32_bf16(a, s0[i], a0, 0, 0, 0);
            a1 = __builtin_amdgcn_mfma_f32_16x16x32_bf16(a, s1[i], a1, 0, 0, 0);
        }
        #pragma unroll
        for (int r = 0; r < 4; ++r) {
            T_s[kg*4 + r][e0]      = f2b(a0[r]);
            T_s[kg*4 + r][e0 + 16] = f2b(a1[r]);
        }
    }
    __syncthreads();

    // ---- P4: OUT[8m x 128e] = T @ Wop + bop (8 MFMA), store m<8 only ----
    {
        f32x4 acc0 = {bb0, bb0, bb0, bb0};
        f32x4 acc1 = {bb1, bb1, bb1, bb1};
        #pragma unroll
        for (int i = 0; i < 4; ++i) {
            short8 a2 = *(const short8*)&T_s[frm][i*32 + kg*8];
            acc0 = __builtin_amdgcn_mfma_f32_16x16x32_bf16(a2, w0[i], acc0, 0, 0, 0);
            acc1 = __builtin_amdgcn_mfma_f32_16x16x32_bf16(a2, w1[i], acc1, 0, 0, 0);
        }
        float* ob = out + ((size_t)(bn*NM + m0))*128;
        if (kg < 2) {
            #pragma unroll
            for (int r = 0; r < 4; ++r) {
                int m = kg*4 + r;
                ob[m*128 + e0]      = acc0[r];
                ob[m*128 + e0 + 16] = acc1[r];
            }
        }
    }
}

extern "C" void kernel_launch(void* const* d_in, const int* in_sizes, int n_in,
                              void* d_out, int out_size, void* d_ws, size_t ws_size,
                              hipStream_t stream) {
    const float* agent = (const float*)d_in[0];
    const float* lane  = (const float*)d_in[1];
    const float* We = (const float*)d_in[2];
    const float* be = (const float*)d_in[3];
    const float* Wa = (const float*)d_in[4];
    const float* ba = (const float*)d_in[5];
    const float* pe = (const float*)d_in[6];
    const float* Wq = (const float*)d_in[7];
    const float* bq = (const float*)d_in[8];
    const float* Wk = (const float*)d_in[9];
    const float* bk = (const float*)d_in[10];
    const float* Wv = (const float*)d_in[11];
    const float* bv = (const float*)d_in[12];
    const float* Wo = (const float*)d_in[13];
    const float* bo = (const float*)d_in[14];
    const float* Wp = (const float*)d_in[15];
    const float* bp = (const float*)d_in[16];
    float* ws  = (float*)d_ws;
    float* out = (float*)d_out;

    hipLaunchKernelGGL(kA, dim3(106), dim3(256), 0, stream,
                       We, be, Wa, ba, pe, Wq, bq, Wk, bk, Wv, bv, Wo, bo, Wp, bp, ws);
    hipLaunchKernelGGL(k_main, dim3(NB*NN*8), dim3(256), 0, stream,
                       agent, lane, ws, out);
}

// Round 14
// 18.132 us; speedup vs baseline: 1.2602x; 1.1765x over previous
//
#include <hip/hip_runtime.h>
#include <hip/hip_bf16.h>

#define L_ 30
#define NB 2
#define NN 64
#define NM 64
#define MCH 16

// ws float offsets
#define O_WAWQ 0        // 12x128
#define O_BQQ  1536     // 128
#define O_CK   1664     // 30x128
#define O_WEWK 5504     // 4x128
#define O_BOP  6016     // 128
#define O_SCT  6144     // ushort[128 c][168 k]  scal^T (masked-dense, bf16)
#define O_WOPT 16896    // ushort[128 e][128 c]  Wop^T (bf16)

typedef __attribute__((ext_vector_type(8))) short short8;
typedef __attribute__((ext_vector_type(4))) float f32x4;

__device__ __forceinline__ unsigned short f2b(float v) {
    union { float f; unsigned int u; } x; x.f = v;
    unsigned int u = x.u + 0x7FFFu + ((x.u >> 16) & 1u);
    return (unsigned short)(u >> 16);
}
__device__ __forceinline__ float dot4(float4 a, float4 b) {
    return a.x*b.x + a.y*b.y + a.z*b.z + a.w*b.w;
}

// kA: ALL weight-only products, depth-1, thread-per-output, e=lane coalesced.
// Row check: 128(WopT)+30(CV')+4(WeWv)+30(Ck)+4(WeWk)+12(WaWq) = 208 rows
// over 104 pair-blocks [0,104) ... wait: 64+15+2+15+2+6 = 104 pair-blocks,
// + block 104 (bqq/bop) + block 105 (SCT pad) = 106 blocks total.
__global__ __launch_bounds__(256)
void kA(const float* __restrict__ We,  const float* __restrict__ be,
        const float* __restrict__ Wa,  const float* __restrict__ ba,
        const float* __restrict__ pe,
        const float* __restrict__ Wq,  const float* __restrict__ bq,
        const float* __restrict__ Wk,  const float* __restrict__ bk,
        const float* __restrict__ Wv,  const float* __restrict__ bv,
        const float* __restrict__ Wo,  const float* __restrict__ bo,
        const float* __restrict__ Wp,  const float* __restrict__ bp,
        float* __restrict__ ws) {
    const int t = threadIdx.x;
    const int b = blockIdx.x;
    const int e = t & 127;
    const int rr = t >> 7;
    unsigned short* SCT  = (unsigned short*)(ws + O_SCT);
    unsigned short* WOPT = (unsigned short*)(ws + O_WOPT);

    if (b < 64) {                       // WopT[e][d] = Wo[d] @ Wp[:,e]
        const int d = 2*b + rr;
        const float* wo = Wo + d*128;
        float acc = 0.f;
        #pragma unroll 32
        for (int x = 0; x < 128; ++x) acc += wo[x] * Wp[x*128 + e];
        WOPT[e*128 + d] = f2b(acc);
    } else if (b < 79) {                // CV'[l][c]=(be+pe_l)@Wv[:,c]+bv -> SCT D-rows
        const int l = 2*(b-64) + rr;
        const int h = e >> 5;
        const float* pl = pe + l*128;
        float acc = bv[e];
        #pragma unroll 32
        for (int d = 0; d < 128; ++d) acc += (be[d] + pl[d]) * Wv[d*128 + e];
        unsigned short v = f2b(acc);
        #pragma unroll
        for (int hh = 0; hh < 4; ++hh)
            SCT[e*168 + 16 + hh*30 + l] = (hh == h) ? v : (unsigned short)0;
    } else if (b < 81) {                // WeWv[j][c] -> SCT P-rows
        const int j = 2*(b-79) + rr;
        const int h = e >> 5;
        const float* wj = We + j*128;
        float acc = 0.f;
        #pragma unroll 32
        for (int d = 0; d < 128; ++d) acc += wj[d] * Wv[d*128 + e];
        unsigned short v = f2b(acc);
        #pragma unroll
        for (int hh = 0; hh < 4; ++hh)
            SCT[e*168 + hh*4 + j] = (hh == h) ? v : (unsigned short)0;
    } else if (b < 96) {                // Ck[l][e] = (be+pe_l)@Wk[:,e]+bk
        const int l = 2*(b-81) + rr;
        const float* pl = pe + l*128;
        float acc = bk[e];
        #pragma unroll 32
        for (int d = 0; d < 128; ++d) acc += (be[d] + pl[d]) * Wk[d*128 + e];
        ws[O_CK + l*128 + e] = acc;
    } else if (b < 98) {                // WeWk[j][e]
        const int j = 2*(b-96) + rr;
        const float* wj = We + j*128;
        float acc = 0.f;
        #pragma unroll 32
        for (int d = 0; d < 128; ++d) acc += wj[d] * Wk[d*128 + e];
        ws[O_WEWK + j*128 + e] = acc;
    } else if (b < 104) {               // WaWq[f][e]
        const int f = 2*(b-98) + rr;
        const float* wf = Wa + f*128;
        float acc = 0.f;
        #pragma unroll 32
        for (int d = 0; d < 128; ++d) acc += wf[d] * Wq[d*128 + e];
        ws[O_WAWQ + f*128 + e] = acc;
    } else if (b == 104) {
        if (rr == 0) {                  // bqq[e] = ba@Wq[:,e] + bq[e]
            float acc = bq[e];
            #pragma unroll 32
            for (int d = 0; d < 128; ++d) acc += ba[d] * Wq[d*128 + e];
            ws[O_BQQ + e] = acc;
        } else {                        // bop[e] = bo@Wp[:,e] + bp[e]
            float acc = bp[e];
            #pragma unroll 32
            for (int d = 0; d < 128; ++d) acc += bo[d] * Wp[d*128 + e];
            ws[O_BOP + e] = acc;
        }
    } else {                            // pad SCT cols 136..167
        for (int i = t; i < 128*32; i += 256) {
            int c = i >> 5, k = 136 + (i & 31);
            SCT[c*168 + k] = 0;
        }
    }
}

// 512 blocks, 16 m's each. P0 {frag prefetch, qs, edges} / P1 {u,c}
// / P2 {scores+softmax+we4} / P3 {T = Wc@scalT, 10 MFMA} / P4 {out = T@Wop + bop}
__global__ __launch_bounds__(256)
void k_main(const float* __restrict__ agent, const float* __restrict__ lane,
            const float* __restrict__ ws, float* __restrict__ out) {

    __shared__ __align__(16) float ScE[MCH][124];             // edges f32 [m][l*4+j]
    __shared__ __align__(16) unsigned short WcB[MCH][168];    // bf16: we4 | w | pad
    __shared__ __align__(16) unsigned short T_s[MCH][136];    // bf16 T
    __shared__ __align__(16) float uc_s[136];                 // u(16) | c(120)
    __shared__ __align__(16) float qs_s[128];

    const int t = threadIdx.x;
    const int bid = blockIdx.x;
    const int bn = bid >> 2;
    const int m0 = (bid & 3) * MCH;
    const int b = bn >> 6;

    // ---- P0 ----
    const unsigned short* SCT  = (const unsigned short*)(ws + O_SCT);
    const unsigned short* WOPT = (const unsigned short*)(ws + O_WOPT);
    const int lane_id = t & 63;
    const int wv = t >> 6;
    const int frm = lane_id & 15;
    const int kg  = lane_id >> 4;
    const int e0 = wv*32 + frm;
    short8 s0[5], s1[5];
    #pragma unroll
    for (int i = 0; i < 5; ++i) {
        s0[i] = *(const short8*)&SCT[e0*168 + i*32 + kg*8];
        s1[i] = *(const short8*)&SCT[(e0+16)*168 + i*32 + kg*8];
    }
    short8 w0[4], w1[4];
    #pragma unroll
    for (int i = 0; i < 4; ++i) {
        w0[i] = *(const short8*)&WOPT[e0*128 + i*32 + kg*8];
        w1[i] = *(const short8*)&WOPT[(e0+16)*128 + i*32 + kg*8];
    }
    const float bb0 = ws[O_BOP + e0];
    const float bb1 = ws[O_BOP + e0 + 16];

    if (t < 128) {                       // qs
        const float* ag = agent + bn*16;
        float acc = ws[O_BQQ + t];
        acc += ag[2] * ws[O_WAWQ + t];
        #pragma unroll
        for (int f = 1; f < 12; ++f) acc += ag[4+f] * ws[O_WAWQ + f*128 + t];
        qs_s[t] = acc * 0.17677669529663687f;
    }
    for (int i = t; i < MCH*32; i += 256) {      // WcB pad cols 136..167
        int m = i >> 5;
        WcB[m][136 + (i & 31)] = 0;
    }
    const float ax  = agent[bn*16+0], ay = agent[bn*16+1];
    const float as_ = agent[bn*16+3], ac = agent[bn*16+4];
    const float f1 = (ax==0.f && ay==0.f && as_==0.f && ac==0.f) ? 0.f : 1.f;
    for (int job = t; job < MCH*30; job += 256) {
        int m = job / 30, l = job - m*30;
        const float* lp = lane + (size_t)((b*NM + m0 + m)*L_ + l)*4;
        float4 lv = *(const float4*)lp;
        float f2 = (lv.x==0.f && lv.y==0.f && lv.z==0.f && lv.w==0.f) ? 0.f : 1.f;
        float f = f1 * f2;
        float dx = lv.x - ax, dy = lv.y - ay;
        float4 ev;
        ev.x = (ac*dx + as_*dy) * 0.1f * f;
        ev.y = (ac*dy - as_*dx) * 0.1f * f;
        ev.z = (lv.z*ac - lv.w*as_) * f;
        ev.w = (lv.w*ac + lv.z*as_) * f;
        *(float4*)&ScE[m][l*4] = ev;
    }
    __syncthreads();

    // ---- P1: u (4x4), c (4x30) from qs_s ----
    if (t < 136) {
        float a = 0.f;
        if (t < 16) {
            int h = t >> 2, j = t & 3;
            const float4* x = (const float4*)(ws + O_WEWK + j*128 + h*32);
            const float4* y = (const float4*)&qs_s[h*32];
            #pragma unroll
            for (int i = 0; i < 8; ++i) a += dot4(x[i], y[i]);
        } else {
            int r = t - 16; int h = r/30, l = r - h*30;
            const float4* x = (const float4*)(ws + O_CK + l*128 + h*32);
            const float4* y = (const float4*)&qs_s[h*32];
            #pragma unroll
            for (int i = 0; i < 8; ++i) a += dot4(x[i], y[i]);
        }
        uc_s[t] = a;
    }
    __syncthreads();

    // ---- P2: scores + 4-lane softmax + fused we4 ----
    {
        const int m = t >> 4, hh = (t >> 2) & 3, s = t & 3;
        float4 u4 = *(const float4*)&uc_s[hh*4];
        float4 e4[8];
        float sc[8];
        float mx = -1e30f;
        #pragma unroll
        for (int k = 0; k < 8; ++k) {
            int l = s + 4*k;
            if (l < 30) {
                e4[k] = *(const float4*)&ScE[m][l*4];
                sc[k] = e4[k].x*u4.x + e4[k].y*u4.y + e4[k].z*u4.z + e4[k].w*u4.w
                      + uc_s[16 + hh*30 + l];
            } else {
                e4[k] = make_float4(0.f,0.f,0.f,0.f);
                sc[k] = -1e30f;
            }
            mx = fmaxf(mx, sc[k]);
        }
        mx = fmaxf(mx, __shfl_xor(mx, 1, 64));
        mx = fmaxf(mx, __shfl_xor(mx, 2, 64));
        float sum = 0.f;
        float wvv[8];
        #pragma unroll
        for (int k = 0; k < 8; ++k) {
            float evv = __expf(sc[k] - mx);
            evv = (s + 4*k < 30) ? evv : 0.f;
            wvv[k] = evv; sum += evv;
        }
        sum += __shfl_xor(sum, 1, 64);
        sum += __shfl_xor(sum, 2, 64);
        const float inv = 1.f / sum;
        float4 p = make_float4(0.f,0.f,0.f,0.f);
        #pragma unroll
        for (int k = 0; k < 8; ++k) {
            int l = s + 4*k;
            if (l < 30) {
                float w = wvv[k] * inv;
                WcB[m][16 + hh*30 + l] = f2b(w);
                p.x += w * e4[k].x; p.y += w * e4[k].y;
                p.z += w * e4[k].z; p.w += w * e4[k].w;
            }
        }
        p.x += __shfl_xor(p.x, 1, 64); p.y += __shfl_xor(p.y, 1, 64);
        p.z += __shfl_xor(p.z, 1, 64); p.w += __shfl_xor(p.w, 1, 64);
        p.x += __shfl_xor(p.x, 2, 64); p.y += __shfl_xor(p.y, 2, 64);
        p.z += __shfl_xor(p.z, 2, 64); p.w += __shfl_xor(p.w, 2, 64);
        float mine = (s == 0) ? p.x : (s == 1) ? p.y : (s == 2) ? p.z : p.w;
        WcB[m][hh*4 + s] = f2b(mine);
    }
    __syncthreads();

    // ---- P3: T[16m x 128c] = WcB[16x160] @ scalT (10 MFMA) -> T_s bf16 ----
    {
        f32x4 a0 = {0.f,0.f,0.f,0.f};
        f32x4 a1 = {0.f,0.f,0.f,0.f};
        #pragma unroll
        for (int i = 0; i < 5; ++i) {
            short8 a = *(const short8*)&WcB[frm][i*32 + kg*8];
            a0 = __builtin_amdgcn_mfma_f32_16x16x32_bf16(a, s0[i], a0, 0, 0, 0);
            a1 = __builtin_amdgcn_mfma_f32_16x16x32_bf16(a, s1[i], a1, 0, 0, 0);
        }
        #pragma unroll
        for (int r = 0; r < 4; ++r) {
            T_s[kg*4 + r][e0]      = f2b(a0[r]);
            T_s[kg*4 + r][e0 + 16] = f2b(a1[r]);
        }
    }
    __syncthreads();

    // ---- P4: OUT[16m x 128e] = T[16x128] @ Wop (8 MFMA), acc init = bop ----
    {
        f32x4 acc0 = {bb0, bb0, bb0, bb0};
        f32x4 acc1 = {bb1, bb1, bb1, bb1};
        #pragma unroll
        for (int i = 0; i < 4; ++i) {
            short8 a2 = *(const short8*)&T_s[frm][i*32 + kg*8];
            acc0 = __builtin_amdgcn_mfma_f32_16x16x32_bf16(a2, w0[i], acc0, 0, 0, 0);
            acc1 = __builtin_amdgcn_mfma_f32_16x16x32_bf16(a2, w1[i], acc1, 0, 0, 0);
        }
        float* ob = out + ((size_t)(bn*NM + m0))*128;
        #pragma unroll
        for (int r = 0; r < 4; ++r) {
            int m = kg*4 + r;
            ob[m*128 + e0]      = acc0[r];
            ob[m*128 + e0 + 16] = acc1[r];
        }
    }
}

extern "C" void kernel_launch(void* const* d_in, const int* in_sizes, int n_in,
                              void* d_out, int out_size, void* d_ws, size_t ws_size,
                              hipStream_t stream) {
    const float* agent = (const float*)d_in[0];
    const float* lane  = (const float*)d_in[1];
    const float* We = (const float*)d_in[2];
    const float* be = (const float*)d_in[3];
    const float* Wa = (const float*)d_in[4];
    const float* ba = (const float*)d_in[5];
    const float* pe = (const float*)d_in[6];
    const float* Wq = (const float*)d_in[7];
    const float* bq = (const float*)d_in[8];
    const float* Wk = (const float*)d_in[9];
    const float* bk = (const float*)d_in[10];
    const float* Wv = (const float*)d_in[11];
    const float* bv = (const float*)d_in[12];
    const float* Wo = (const float*)d_in[13];
    const float* bo = (const float*)d_in[14];
    const float* Wp = (const float*)d_in[15];
    const float* bp = (const float*)d_in[16];
    float* ws  = (float*)d_ws;
    float* out = (float*)d_out;

    hipLaunchKernelGGL(kA, dim3(106), dim3(256), 0, stream,
                       We, be, Wa, ba, pe, Wq, bq, Wk, bk, Wv, bv, Wo, bo, Wp, bp, ws);
    hipLaunchKernelGGL(k_main, dim3(NB*NN*4), dim3(256), 0, stream,
                       agent, lane, ws, out);
}